// Round 6
// baseline (199.165 us; speedup 1.0000x reference)
//
#include <hip/hip_runtime.h>
#include <hip/hip_bf16.h>

// CARAFE R12 = R11 (141.6 us anchor) + k_fused_out v9:
//  - ALL 4 og per block (1024 blocks: pt x n). Tap loop loads 4 zf (one per
//    og, 256B apart in the SAME 1KB o-block -> every zT line fully consumed
//    by one block; was 4 blocks each fetching 1/4 of it) + 1 kf -> 64
//    independent FMAs. 4x MLP per dependency window, 64 indep acc chains.
//  - Kern tile staged + softmaxed once per (pt,n): half of R11's count.
//  - acc[4][4][4] fully unrolled (static idx); __launch_bounds__(256,3).
//  - k_prep, k_dzmfma (v2), k_encmfma unchanged (verified).
// Same FMA order per acc element -> absmax must stay 0.015625.
// Pipeline: 4 dispatches. N=4, H=W=64, INC=256, CM=64, KUP=5, DELTA=2,
// enc_out=100, OUTC=256.

namespace {
constexpr int kN = 4, kH = 64, kW = 64, kINC = 256, kCM = 64;
constexpr int kENC = 100, kH2 = 128, kW2 = 128, kOUTC = 256;
constexpr int kHW = kH * kW;       // 4096
constexpr int kHW2 = kH2 * kW2;    // 16384
constexpr int kPadW = 66;          // 64 + 1 halo (enc 3x3)
constexpr int kTImg = kPadW * kPadW * kCM;    // 278784 (downT per image)
constexpr int kZPad = 68;          // 64 + 2 halo (reassembly 5x5)
constexpr int kZImg = kZPad * kZPad * kOUTC;  // 1183744 (zT per image)
constexpr int kXP = 264;           // x-tile LDS pitch in shorts
// k_prep thread-range boundaries (all block-aligned except final tail):
constexpr int kPrepRepackEnc = 9 * 7 * 2 * 512;          // 64512  (252 blocks)
constexpr int kPrepRepackWoz = 8 * 20 * 512;             // 81920  (320 blocks)
constexpr int kPrepHaloZ = 4 * 528 * 16;                 // 33792
constexpr int kPrepHaloD = 4 * 260 * 8;                  // 8320
constexpr int kPrepTotal = kPrepRepackEnc + kPrepRepackWoz + kPrepHaloZ + kPrepHaloD; // 188544
}

typedef __attribute__((ext_vector_type(8))) short short8;   // 8 bf16
typedef __attribute__((ext_vector_type(4))) float floatx4;  // MFMA acc

static __device__ __forceinline__ unsigned short bf16bits(float f) {
  __hip_bfloat16 h = __float2bfloat16(f);
  return *(unsigned short*)&h;
}

// ---------- merged prep: weight repacks + halo clears (one dispatch) ----------
__global__ __launch_bounds__(256) void k_prep(
    const float* __restrict__ we, unsigned short* __restrict__ Aswz,
    const float* __restrict__ wd, const float* __restrict__ wo,
    unsigned short* __restrict__ Awoz,
    float* __restrict__ zT, __hip_bfloat16* __restrict__ downT) {
  const int t = blockIdx.x * 256 + threadIdx.x;
  if (t < kPrepRepackEnc) {
    const int e = t;
    const int j = e & 7, lane = (e >> 3) & 63, kh = (e >> 9) & 1, tm = e >> 10;
    const int mt = tm % 7, tap = tm / 7;
    const int o = mt * 16 + (lane & 15);
    const int ci = kh * 32 + ((lane >> 4) & 3) * 8 + j;
    const float v = (o < kENC) ? we[(size_t)o * 576 + ci * 9 + tap] : 0.f;
    Aswz[e] = bf16bits(v);
  } else if (t < kPrepRepackEnc + kPrepRepackWoz) {
    const int e = t - kPrepRepackEnc;
    const int j = e & 7, lane = (e >> 3) & 63;
    const int rest = e >> 9;
    const int mt = rest % 20, ks = rest / 20;
    const int r = mt * 16 + (lane & 15);
    const int k = ks * 32 + (lane >> 4) * 8 + j;
    const float v = (r < kCM) ? wd[(size_t)r * kINC + k]
                              : wo[(size_t)(r - kCM) * kINC + k];
    Awoz[e] = bf16bits(v);
  } else if (t < kPrepTotal) {
    const int u0 = t - (kPrepRepackEnc + kPrepRepackWoz);
    if (u0 < kPrepHaloZ) {
      const int chunk = u0 & 15, rest = u0 >> 4;
      const int i = rest % 528, n = rest / 528;
      int r, c;
      if (i < 272) { r = i / 68; if (r >= 2) r += 64; c = i % 68; }
      else { const int j = i - 272; r = 2 + (j >> 2); const int cc = j & 3; c = (cc < 2) ? cc : cc + 64; }
      float4* p = (float4*)(zT + (size_t)n * kZImg + ((size_t)r * kZPad + c) * kOUTC) + chunk;
      *p = make_float4(0.f, 0.f, 0.f, 0.f);
    } else {
      const int u = u0 - kPrepHaloZ;
      const int chunk = u & 7, rest = u >> 3;
      const int i = rest % 260, n = rest / 260;
      int r, c;
      if (i < 132) { r = (i / 66) ? 65 : 0; c = i % 66; }
      else { const int j = i - 132; r = 1 + (j >> 1); c = (j & 1) ? 65 : 0; }
      float4* p = (float4*)((char*)downT
                  + ((size_t)n * kTImg + ((size_t)r * kPadW + c) * kCM) * 2) + chunk;
      *p = make_float4(0.f, 0.f, 0.f, 0.f);
    }
  }
}

// ---------- fused down + z GEMM: M=320, K=256, N=16384 (v2, verified) ----------
__global__ __launch_bounds__(256) void k_dzmfma(
    const float* __restrict__ x, const unsigned short* __restrict__ Awoz,
    const float* __restrict__ bd, __hip_bfloat16* __restrict__ downT,
    float* __restrict__ zT) {
  const int b = blockIdx.x;
  const int pt = b & 255, n = b >> 8;
  const int wave = threadIdx.x >> 6, lane = threadIdx.x & 63;
  const int col = lane & 15, quad = lane >> 4;
  const int px = pt * 16 + col;
  const int h = px >> 6, w = px & 63;

  __shared__ unsigned short xlds[16 * kXP];    // [px][ch] bf16, 8448 B

  // --- stage x tile: wave w handles ksteps {2w, 2w+1} ---
  {
    const float* xb = x + (size_t)n * kINC * kHW + px;
#pragma unroll
    for (int ki = 0; ki < 2; ++ki) {
      const int ks = wave * 2 + ki;
      float xv[8];
#pragma unroll
      for (int j = 0; j < 8; ++j)
        xv[j] = xb[(size_t)(ks * 32 + quad * 8 + j) * kHW];
      short8 bf;
#pragma unroll
      for (int j = 0; j < 8; ++j) bf[j] = (short)bf16bits(xv[j]);
      *(short8*)(xlds + col * kXP + ks * 32 + quad * 8) = bf;
    }
  }
  __syncthreads();

  floatx4 acc[5];
#pragma unroll
  for (int m = 0; m < 5; ++m) acc[m] = (floatx4){0.f, 0.f, 0.f, 0.f};

#pragma unroll
  for (int ks = 0; ks < 8; ++ks) {
    const short8 bf = *(const short8*)(xlds + col * kXP + ks * 32 + quad * 8);
#pragma unroll
    for (int m = 0; m < 5; ++m) {
      const int wtile = wave * 5 + m;
      const short8 af = *(const short8*)(
          Awoz + ((size_t)(ks * 20 + wtile) * 64 + lane) * 8);
      acc[m] = __builtin_amdgcn_mfma_f32_16x16x32_bf16(af, bf, acc[m], 0, 0, 0);
    }
  }

#pragma unroll
  for (int m = 0; m < 5; ++m) {
    const int wtile = wave * 5 + m;
    const int r0 = wtile * 16 + quad * 4;
    if (wtile < 4) {
      union { unsigned short u[4]; uint2 v; } pk;
#pragma unroll
      for (int rr = 0; rr < 4; ++rr)
        pk.u[rr] = bf16bits(acc[m][rr] + bd[r0 + rr]);
      __hip_bfloat16* dst = downT + (size_t)n * kTImg
                            + ((h + 1) * kPadW + (w + 1)) * kCM + r0;
      *(uint2*)dst = pk.v;
    } else {
      const int o = r0 - kCM;
      float* dst = zT + (size_t)n * kZImg
                   + ((h + 2) * kZPad + (w + 2)) * kOUTC + o;
      *(float4*)dst = make_float4(acc[m][0], acc[m][1], acc[m][2], acc[m][3]);
    }
  }
}

// ---------- enc conv as MFMA GEMM -> enc fp32 (N,100,64,64) (R4, verified) ----------
// Writes RAW (pre-softmax) enc; softmax happens inside k_fused_out.
__global__ __launch_bounds__(256) void k_encmfma(
    const __hip_bfloat16* __restrict__ downT,
    const unsigned short* __restrict__ Aswz,
    const float* __restrict__ be, float* __restrict__ enc) {
  const int b = blockIdx.x;                 // 1024: h(64) x mtp(4) x n(4)
  const int h = b & 63, mtp = (b >> 6) & 3, n = b >> 8;
  const int wave = threadIdx.x >> 6, lane = threadIdx.x & 63;
  const int w0 = wave << 4;
  const int col = lane & 15, quad = lane >> 4;
  const int mt0 = mtp * 2;
  const bool has2 = (mt0 + 1) < 7;
  const short* dT = (const short*)downT + (size_t)n * kTImg;
  floatx4 acc0 = {0.f, 0.f, 0.f, 0.f}, acc1 = {0.f, 0.f, 0.f, 0.f};
#pragma unroll
  for (int tap = 0; tap < 9; ++tap) {
    const int dh = tap / 3 - 1, dw = tap % 3 - 1;
    const int rowbase = ((h + 1 + dh) * kPadW + (w0 + col + 1 + dw)) * kCM
                        + quad * 8;
#pragma unroll
    for (int kh = 0; kh < 2; ++kh) {
      const short8 bf = *(const short8*)(dT + rowbase + kh * 32);
      const short8 a0 = *(const short8*)(
          Aswz + (((size_t)(tap * 7 + mt0) * 2 + kh) * 64 + lane) * 8);
      acc0 = __builtin_amdgcn_mfma_f32_16x16x32_bf16(a0, bf, acc0, 0, 0, 0);
      if (has2) {
        const short8 a1 = *(const short8*)(
            Aswz + (((size_t)(tap * 7 + mt0 + 1) * 2 + kh) * 64 + lane) * 8);
        acc1 = __builtin_amdgcn_mfma_f32_16x16x32_bf16(a1, bf, acc1, 0, 0, 0);
      }
    }
  }
  const int p = h * kW + w0 + col;
#pragma unroll
  for (int r = 0; r < 4; ++r) {
    const int o = mt0 * 16 + quad * 4 + r;
    if (o < kENC) enc[(size_t)(n * kENC + o) * kHW + p] = acc0[r] + be[o];
  }
  if (has2) {
#pragma unroll
    for (int r = 0; r < 4; ++r) {
      const int o = (mt0 + 1) * 16 + quad * 4 + r;
      if (o < kENC) enc[(size_t)(n * kENC + o) * kHW + p] = acc1[r] + be[o];
    }
  }
}

// ---------- fused softmax + reassembly + pixel shuffle + bias -> out (v9) ----------
// 1024 blocks: pt(256) x n(4); 256 thr = 4 waves. Each block does ALL 4 og.
// Phase 1a: stage RAW kern[16 px][100 ch] in LDS (coalesced).
// Phase 1b: wave-parallel softmax (64 (px,d) pairs x 4 workers, shfl_xor).
// Phase 2: 25 taps: per tap 1 kern ds_read_b128 + 4 z float4 (one per og,
//   256B apart in the same 1KB o-block -> full line consumption, 4x MLP)
//   -> 64 independent FMAs into acc[4][4][4].
// Phase 3 (per og): transpose via scratch (stride-65) -> coalesced stores.
__global__ __launch_bounds__(256, 3) void k_fused_out(
    const float* __restrict__ zT, const float* __restrict__ enc,
    const float* __restrict__ bo, float* __restrict__ out) {
  const int b = blockIdx.x;
  const int pt = b & 255, n = b >> 8;
  const int tid = threadIdx.x;
  const int wave = tid >> 6, lane = tid & 63;
  const int h = pt >> 2, w0 = (pt & 3) << 4;   // 16-px segment [w0, w0+16)
  const int px0 = pt * 16;                     // linear px base

  __shared__ float lds[1664 + 4160];           // 23.3 KB
  float* kernLDS = lds;                        // [16 px][104] (pad 100->104)
  float* scr = lds + 1664;                     // transpose scratch [64][65]

  // --- phase 1a: stage raw kern tile ---
  {
    const int p = tid & 15, chb = tid >> 4;
#pragma unroll
    for (int r = 0; r < 7; ++r) {
      const int ch = r * 16 + chb;
      if (ch < kENC)
        kernLDS[p * 104 + ch] = enc[((size_t)n * kENC + ch) * kHW + px0 + p];
    }
  }
  __syncthreads();

  // --- phase 1b: wave-parallel softmax over 25 taps ---
  {
    const int pair = tid >> 2, q = tid & 3;
    const int p = pair >> 2, d = pair & 3;
    float* kb = kernLDS + p * 104 + d;         // taps at stride 4 floats
    const int start = q ? (1 + 6 * q) : 0;
    const int count = q ? 6 : 7;
    float v[7];
    float m = -1e30f;
#pragma unroll
    for (int k = 0; k < 7; ++k)
      if (k < count) { v[k] = kb[(start + k) * 4]; m = fmaxf(m, v[k]); }
    m = fmaxf(m, __shfl_xor(m, 1));
    m = fmaxf(m, __shfl_xor(m, 2));
    float s = 0.f;
#pragma unroll
    for (int k = 0; k < 7; ++k)
      if (k < count) { v[k] = __expf(v[k] - m); s += v[k]; }
    s += __shfl_xor(s, 1);
    s += __shfl_xor(s, 2);
    const float inv = 1.f / s;
#pragma unroll
    for (int k = 0; k < 7; ++k)
      if (k < count) kb[(start + k) * 4] = v[k] * inv;
  }
  __syncthreads();

  // --- phase 2: 25 taps, all 4 og ---
  const int oc = lane & 15, pxi = lane >> 4;
  const int px_l = wave * 4 + pxi;             // [0,16)
  const int w = w0 + px_l;
  const int o_l = oc * 4;                      // [0,64) step 4
  const float* kp = kernLDS + px_l * 104;
  const float* zrow0 = zT + (size_t)n * kZImg + o_l;
  float acc[4][4][4] = {};                     // [og][oi][d], static idx only
#pragma unroll
  for (int tap = 0; tap < 25; ++tap) {
    const int kh = tap / 5, kw = tap % 5;      // z idx: (h+2 + kh-2) = h+kh
    const float* zrow = zrow0 + ((size_t)(h + kh) * kZPad + (w + kw)) * kOUTC;
    const float4 kf = *(const float4*)(kp + tap * 4);
    const float kc[4] = {kf.x, kf.y, kf.z, kf.w};
#pragma unroll
    for (int og = 0; og < 4; ++og) {
      const float4 zf = *(const float4*)(zrow + og * 64);
      const float zc[4] = {zf.x, zf.y, zf.z, zf.w};
#pragma unroll
      for (int oi = 0; oi < 4; ++oi)
#pragma unroll
        for (int d = 0; d < 4; ++d)
          acc[og][oi][d] += zc[oi] * kc[d];
    }
  }

  // --- phase 3: per og, transpose via scratch, coalesced stores ---
  const int ol2 = tid >> 2, q2 = tid & 3;      // store-phase mapping
#pragma unroll
  for (int og = 0; og < 4; ++og) {
    __syncthreads();                           // scratch free (prev stores done)
#pragma unroll
    for (int oi = 0; oi < 4; ++oi)
#pragma unroll
      for (int d = 0; d < 4; ++d)
        scr[(o_l + oi) * 65 + px_l * 4 + d] = acc[og][oi][d];
    __syncthreads();

    const int o = og * 64 + ol2;
    const float bias = bo[o];
    const float* Trow = scr + ol2 * 65;
#pragma unroll
    for (int i = 0; i < 2; ++i) {
      float* row = out + ((size_t)(n * kOUTC + o) * kH2 + (2 * h + i)) * kW2 + 2 * w0;
#pragma unroll
      for (int s = 0; s < 2; ++s) {
        const int xb_ = s * 16 + q2 * 4;       // x offset in [0,32)
        float4 v;
        v.x = Trow[((xb_ + 0) >> 1) * 4 + i * 2 + ((xb_ + 0) & 1)] + bias;
        v.y = Trow[((xb_ + 1) >> 1) * 4 + i * 2 + ((xb_ + 1) & 1)] + bias;
        v.z = Trow[((xb_ + 2) >> 1) * 4 + i * 2 + ((xb_ + 2) & 1)] + bias;
        v.w = Trow[((xb_ + 3) >> 1) * 4 + i * 2 + ((xb_ + 3) & 1)] + bias;
        *(float4*)(row + xb_) = v;
      }
    }
  }
}

extern "C" void kernel_launch(void* const* d_in, const int* in_sizes, int n_in,
                              void* d_out, int out_size, void* d_ws, size_t ws_size,
                              hipStream_t stream) {
  const float* x  = (const float*)d_in[0];   // (4,256,64,64)
  const float* wd = (const float*)d_in[1];   // (64,256,1,1)
  const float* bd = (const float*)d_in[2];   // (64,)
  const float* we = (const float*)d_in[3];   // (100,64,3,3)
  const float* be = (const float*)d_in[4];   // (100,)
  const float* wo = (const float*)d_in[5];   // (256,256,1,1)
  const float* bo = (const float*)d_in[6];   // (256,)
  float* out = (float*)d_out;                // (4,256,128,128)

  // workspace (all 16B-aligned):
  float* enc = (float*)d_ws;                          // 1,638,400 f
  float* zT  = enc + 1638400;                         // 4,734,976 f (padded 68x68)
  __hip_bfloat16* downT = (__hip_bfloat16*)(zT + 4734976);      // 1,115,136 bf16
  unsigned short* Aswz  = (unsigned short*)(downT + (size_t)kN * kTImg); // 64,512
  unsigned short* Awoz  = Aswz + 64512;                          // 81,920

  // 4 dispatches: prep(repacks+halo) -> dz GEMM -> enc GEMM -> fused out
  k_prep<<<737, 256, 0, stream>>>(we, Aswz, wd, wo, Awoz, zT, downT);
  k_dzmfma<<<1024, 256, 0, stream>>>(x, Awoz, bd, downT, zT);
  k_encmfma<<<1024, 256, 0, stream>>>(downT, Aswz, be, enc);
  k_fused_out<<<1024, 256, 0, stream>>>(zT, enc, bo, out);
}

// Round 7
// 143.490 us; speedup vs baseline: 1.3880x; 1.3880x over previous
//
#include <hip/hip_runtime.h>
#include <hip/hip_bf16.h>

// CARAFE R13 = R11 (141.6 us anchor, R12 reverted) + prep-work overlap:
//  - k_prep shrunk to the Awoz repack ONLY (320 blocks) -- the one output
//    k_dzmfma consumes.
//  - Aswz repack + zT/downT halo clears moved INTO the k_dzmfma dispatch as
//    extra blocks 1024..1440 (disjoint writes; consumed only by later
//    dispatches k_encmfma / k_fused_out -> no intra-dispatch ordering need).
//  - k_dzmfma GEMM blocks, k_encmfma, k_fused_out (v8, 2-og) unchanged.
// R12's 4-og fused_out REVERTED: acc[64] spilled to scratch (VGPR=84,
// WRITE 190MB vs 67MB out) and 102KB/block z streams thrashed L2
// (FETCH 110MB = raw request volume, 0% hit).
// Zero arithmetic change vs R11 -> absmax must stay exactly 0.015625.
// Pipeline: 4 dispatches. N=4, H=W=64, INC=256, CM=64, KUP=5, DELTA=2,
// enc_out=100, OUTC=256.

namespace {
constexpr int kN = 4, kH = 64, kW = 64, kINC = 256, kCM = 64;
constexpr int kENC = 100, kH2 = 128, kW2 = 128, kOUTC = 256;
constexpr int kHW = kH * kW;       // 4096
constexpr int kHW2 = kH2 * kW2;    // 16384
constexpr int kPadW = 66;          // 64 + 1 halo (enc 3x3)
constexpr int kTImg = kPadW * kPadW * kCM;    // 278784 (downT per image)
constexpr int kZPad = 68;          // 64 + 2 halo (reassembly 5x5)
constexpr int kZImg = kZPad * kZPad * kOUTC;  // 1183744 (zT per image)
constexpr int kXP = 264;           // x-tile LDS pitch in shorts
// extra-block work ranges inside the k_dzmfma dispatch:
constexpr int kRepackEnc = 9 * 7 * 2 * 512;              // 64512 (252 blocks)
constexpr int kHaloZ = 4 * 528 * 16;                     // 33792
constexpr int kHaloD = 4 * 260 * 8;                      // 8320
constexpr int kExtraTotal = kRepackEnc + kHaloZ + kHaloD;       // 106624
constexpr int kExtraBlocks = (kExtraTotal + 255) / 256;         // 417
constexpr int kRepackWoz = 8 * 20 * 512;                 // 81920 (320 blocks)
}

typedef __attribute__((ext_vector_type(8))) short short8;   // 8 bf16
typedef __attribute__((ext_vector_type(4))) float floatx4;  // MFMA acc

static __device__ __forceinline__ unsigned short bf16bits(float f) {
  __hip_bfloat16 h = __float2bfloat16(f);
  return *(unsigned short*)&h;
}

// ---------- prep: [wd;wo] repack only (consumed by k_dzmfma) ----------
__global__ __launch_bounds__(256) void k_prep(
    const float* __restrict__ wd, const float* __restrict__ wo,
    unsigned short* __restrict__ Awoz) {
  const int e = blockIdx.x * 256 + threadIdx.x;
  if (e >= kRepackWoz) return;
  const int j = e & 7, lane = (e >> 3) & 63;
  const int rest = e >> 9;
  const int mt = rest % 20, ks = rest / 20;
  const int r = mt * 16 + (lane & 15);
  const int k = ks * 32 + (lane >> 4) * 8 + j;
  const float v = (r < kCM) ? wd[(size_t)r * kINC + k]
                            : wo[(size_t)(r - kCM) * kINC + k];
  Awoz[e] = bf16bits(v);
}

// ---------- fused down + z GEMM (v2) + overlapped prep extras ----------
// Blocks [0,1024): GEMM. Blocks [1024,1441): Aswz repack + halo clears
// (outputs consumed only by LATER dispatches; writes disjoint from GEMM's).
__global__ __launch_bounds__(256) void k_dzmfma(
    const float* __restrict__ x, const unsigned short* __restrict__ Awoz,
    const float* __restrict__ bd, __hip_bfloat16* __restrict__ downT,
    float* __restrict__ zT,
    const float* __restrict__ we, unsigned short* __restrict__ Aswz) {
  const int b = blockIdx.x;

  if (b >= 1024) {                      // ---- overlapped prep extras ----
    const int t = (b - 1024) * 256 + threadIdx.x;
    if (t < kRepackEnc) {
      const int e = t;
      const int j = e & 7, lane = (e >> 3) & 63, kh = (e >> 9) & 1, tm = e >> 10;
      const int mt = tm % 7, tap = tm / 7;
      const int o = mt * 16 + (lane & 15);
      const int ci = kh * 32 + ((lane >> 4) & 3) * 8 + j;
      const float v = (o < kENC) ? we[(size_t)o * 576 + ci * 9 + tap] : 0.f;
      Aswz[e] = bf16bits(v);
    } else if (t < kRepackEnc + kHaloZ) {
      const int u0 = t - kRepackEnc;
      const int chunk = u0 & 15, rest = u0 >> 4;
      const int i = rest % 528, n = rest / 528;
      int r, c;
      if (i < 272) { r = i / 68; if (r >= 2) r += 64; c = i % 68; }
      else { const int j = i - 272; r = 2 + (j >> 2); const int cc = j & 3; c = (cc < 2) ? cc : cc + 64; }
      float4* p = (float4*)(zT + (size_t)n * kZImg + ((size_t)r * kZPad + c) * kOUTC) + chunk;
      *p = make_float4(0.f, 0.f, 0.f, 0.f);
    } else if (t < kExtraTotal) {
      const int u = t - kRepackEnc - kHaloZ;
      const int chunk = u & 7, rest = u >> 3;
      const int i = rest % 260, n = rest / 260;
      int r, c;
      if (i < 132) { r = (i / 66) ? 65 : 0; c = i % 66; }
      else { const int j = i - 132; r = 1 + (j >> 1); c = (j & 1) ? 65 : 0; }
      float4* p = (float4*)((char*)downT
                  + ((size_t)n * kTImg + ((size_t)r * kPadW + c) * kCM) * 2) + chunk;
      *p = make_float4(0.f, 0.f, 0.f, 0.f);
    }
    return;
  }

  // ---- GEMM blocks (R11 v2, verified) ----
  const int pt = b & 255, n = b >> 8;
  const int wave = threadIdx.x >> 6, lane = threadIdx.x & 63;
  const int col = lane & 15, quad = lane >> 4;
  const int px = pt * 16 + col;
  const int h = px >> 6, w = px & 63;

  __shared__ unsigned short xlds[16 * kXP];    // [px][ch] bf16, 8448 B

  // --- stage x tile: wave w handles ksteps {2w, 2w+1} ---
  {
    const float* xb = x + (size_t)n * kINC * kHW + px;
#pragma unroll
    for (int ki = 0; ki < 2; ++ki) {
      const int ks = wave * 2 + ki;
      float xv[8];
#pragma unroll
      for (int j = 0; j < 8; ++j)
        xv[j] = xb[(size_t)(ks * 32 + quad * 8 + j) * kHW];
      short8 bf;
#pragma unroll
      for (int j = 0; j < 8; ++j) bf[j] = (short)bf16bits(xv[j]);
      *(short8*)(xlds + col * kXP + ks * 32 + quad * 8) = bf;
    }
  }
  __syncthreads();

  floatx4 acc[5];
#pragma unroll
  for (int m = 0; m < 5; ++m) acc[m] = (floatx4){0.f, 0.f, 0.f, 0.f};

#pragma unroll
  for (int ks = 0; ks < 8; ++ks) {
    const short8 bf = *(const short8*)(xlds + col * kXP + ks * 32 + quad * 8);
#pragma unroll
    for (int m = 0; m < 5; ++m) {
      const int wtile = wave * 5 + m;
      const short8 af = *(const short8*)(
          Awoz + ((size_t)(ks * 20 + wtile) * 64 + lane) * 8);
      acc[m] = __builtin_amdgcn_mfma_f32_16x16x32_bf16(af, bf, acc[m], 0, 0, 0);
    }
  }

#pragma unroll
  for (int m = 0; m < 5; ++m) {
    const int wtile = wave * 5 + m;
    const int r0 = wtile * 16 + quad * 4;
    if (wtile < 4) {
      union { unsigned short u[4]; uint2 v; } pk;
#pragma unroll
      for (int rr = 0; rr < 4; ++rr)
        pk.u[rr] = bf16bits(acc[m][rr] + bd[r0 + rr]);
      __hip_bfloat16* dst = downT + (size_t)n * kTImg
                            + ((h + 1) * kPadW + (w + 1)) * kCM + r0;
      *(uint2*)dst = pk.v;
    } else {
      const int o = r0 - kCM;
      float* dst = zT + (size_t)n * kZImg
                   + ((h + 2) * kZPad + (w + 2)) * kOUTC + o;
      *(float4*)dst = make_float4(acc[m][0], acc[m][1], acc[m][2], acc[m][3]);
    }
  }
}

// ---------- enc conv as MFMA GEMM -> enc fp32 (N,100,64,64) (R4, verified) ----------
// Writes RAW (pre-softmax) enc; softmax happens inside k_fused_out.
__global__ __launch_bounds__(256) void k_encmfma(
    const __hip_bfloat16* __restrict__ downT,
    const unsigned short* __restrict__ Aswz,
    const float* __restrict__ be, float* __restrict__ enc) {
  const int b = blockIdx.x;                 // 1024: h(64) x mtp(4) x n(4)
  const int h = b & 63, mtp = (b >> 6) & 3, n = b >> 8;
  const int wave = threadIdx.x >> 6, lane = threadIdx.x & 63;
  const int w0 = wave << 4;
  const int col = lane & 15, quad = lane >> 4;
  const int mt0 = mtp * 2;
  const bool has2 = (mt0 + 1) < 7;
  const short* dT = (const short*)downT + (size_t)n * kTImg;
  floatx4 acc0 = {0.f, 0.f, 0.f, 0.f}, acc1 = {0.f, 0.f, 0.f, 0.f};
#pragma unroll
  for (int tap = 0; tap < 9; ++tap) {
    const int dh = tap / 3 - 1, dw = tap % 3 - 1;
    const int rowbase = ((h + 1 + dh) * kPadW + (w0 + col + 1 + dw)) * kCM
                        + quad * 8;
#pragma unroll
    for (int kh = 0; kh < 2; ++kh) {
      const short8 bf = *(const short8*)(dT + rowbase + kh * 32);
      const short8 a0 = *(const short8*)(
          Aswz + (((size_t)(tap * 7 + mt0) * 2 + kh) * 64 + lane) * 8);
      acc0 = __builtin_amdgcn_mfma_f32_16x16x32_bf16(a0, bf, acc0, 0, 0, 0);
      if (has2) {
        const short8 a1 = *(const short8*)(
            Aswz + (((size_t)(tap * 7 + mt0 + 1) * 2 + kh) * 64 + lane) * 8);
        acc1 = __builtin_amdgcn_mfma_f32_16x16x32_bf16(a1, bf, acc1, 0, 0, 0);
      }
    }
  }
  const int p = h * kW + w0 + col;
#pragma unroll
  for (int r = 0; r < 4; ++r) {
    const int o = mt0 * 16 + quad * 4 + r;
    if (o < kENC) enc[(size_t)(n * kENC + o) * kHW + p] = acc0[r] + be[o];
  }
  if (has2) {
#pragma unroll
    for (int r = 0; r < 4; ++r) {
      const int o = (mt0 + 1) * 16 + quad * 4 + r;
      if (o < kENC) enc[(size_t)(n * kENC + o) * kHW + p] = acc1[r] + be[o];
    }
  }
}

// ---------- fused softmax + reassembly + pixel shuffle + bias -> out (v8) ----------
// 2048 blocks: pt(256) x oh(2) x n(4); 256 thr = 4 waves. Each block does
// og = {2*oh, 2*oh+1}: kern tile staged + softmaxed ONCE, reused for both.
__global__ __launch_bounds__(256) void k_fused_out(
    const float* __restrict__ zT, const float* __restrict__ enc,
    const float* __restrict__ bo, float* __restrict__ out) {
  const int b = blockIdx.x;
  const int pt = b & 255, oh = (b >> 8) & 1, n = b >> 9;
  const int tid = threadIdx.x;
  const int wave = tid >> 6, lane = tid & 63;
  const int h = pt >> 2, w0 = (pt & 3) << 4;   // 16-px segment [w0, w0+16)
  const int px0 = pt * 16;                     // linear px base

  __shared__ float lds[1664 + 4160];           // 23.3 KB
  float* kernLDS = lds;                        // [16 px][104] (pad 100->104)
  float* scr = lds + 1664;                     // transpose scratch [64][65]

  // --- phase 1a: stage raw kern tile ---
  {
    const int p = tid & 15, chb = tid >> 4;
#pragma unroll
    for (int r = 0; r < 7; ++r) {
      const int ch = r * 16 + chb;
      if (ch < kENC)
        kernLDS[p * 104 + ch] = enc[((size_t)n * kENC + ch) * kHW + px0 + p];
    }
  }
  __syncthreads();

  // --- phase 1b: wave-parallel softmax over 25 taps ---
  {
    const int pair = tid >> 2, q = tid & 3;
    const int p = pair >> 2, d = pair & 3;
    float* kb = kernLDS + p * 104 + d;         // taps at stride 4 floats
    const int start = q ? (1 + 6 * q) : 0;
    const int count = q ? 6 : 7;
    float v[7];
    float m = -1e30f;
#pragma unroll
    for (int k = 0; k < 7; ++k)
      if (k < count) { v[k] = kb[(start + k) * 4]; m = fmaxf(m, v[k]); }
    m = fmaxf(m, __shfl_xor(m, 1));
    m = fmaxf(m, __shfl_xor(m, 2));
    float s = 0.f;
#pragma unroll
    for (int k = 0; k < 7; ++k)
      if (k < count) { v[k] = __expf(v[k] - m); s += v[k]; }
    s += __shfl_xor(s, 1);
    s += __shfl_xor(s, 2);
    const float inv = 1.f / s;
#pragma unroll
    for (int k = 0; k < 7; ++k)
      if (k < count) kb[(start + k) * 4] = v[k] * inv;
  }
  __syncthreads();

  const int oc = lane & 15, pxi = lane >> 4;
  const int px_l = wave * 4 + pxi;             // [0,16)
  const int w = w0 + px_l;
  const int o_l = oc * 4;                      // [0,64) step 4
  const float* kp = kernLDS + px_l * 104;
  const int ol2 = tid >> 2, q2 = tid & 3;      // store-phase mapping

#pragma unroll
  for (int ogi = 0; ogi < 2; ++ogi) {
    const int og = oh * 2 + ogi;

    // --- phase 2: 25 taps, z direct from global (L1/L2-served) ---
    const float* zb = zT + (size_t)n * kZImg + og * 64 + o_l;
    float acc[4][4] = {};                      // [oi][d]
#pragma unroll
    for (int tap = 0; tap < 25; ++tap) {
      const int kh = tap / 5, kw = tap % 5;    // z idx: (h+2 + kh-2) = h+kh
      const float4 zf = *(const float4*)(
          zb + ((size_t)(h + kh) * kZPad + (w + kw)) * kOUTC);
      const float4 kf = *(const float4*)(kp + tap * 4);
      acc[0][0] += zf.x * kf.x; acc[0][1] += zf.x * kf.y; acc[0][2] += zf.x * kf.z; acc[0][3] += zf.x * kf.w;
      acc[1][0] += zf.y * kf.x; acc[1][1] += zf.y * kf.y; acc[1][2] += zf.y * kf.z; acc[1][3] += zf.y * kf.w;
      acc[2][0] += zf.z * kf.x; acc[2][1] += zf.z * kf.y; acc[2][2] += zf.z * kf.z; acc[2][3] += zf.z * kf.w;
      acc[3][0] += zf.w * kf.x; acc[3][1] += zf.w * kf.y; acc[3][2] += zf.w * kf.z; acc[3][3] += zf.w * kf.w;
    }

    // --- phase 3: transpose via scratch, coalesced stores ---
    __syncthreads();                           // scratch free (prev stores done)
#pragma unroll
    for (int oi = 0; oi < 4; ++oi)
#pragma unroll
      for (int d = 0; d < 4; ++d)
        scr[(o_l + oi) * 65 + px_l * 4 + d] = acc[oi][d];
    __syncthreads();

    const int o = og * 64 + ol2;
    const float bias = bo[o];
    const float* Trow = scr + ol2 * 65;
#pragma unroll
    for (int i = 0; i < 2; ++i) {
      float* row = out + ((size_t)(n * kOUTC + o) * kH2 + (2 * h + i)) * kW2 + 2 * w0;
#pragma unroll
      for (int s = 0; s < 2; ++s) {
        const int xb_ = s * 16 + q2 * 4;       // x offset in [0,32)
        float4 v;
        v.x = Trow[((xb_ + 0) >> 1) * 4 + i * 2 + ((xb_ + 0) & 1)] + bias;
        v.y = Trow[((xb_ + 1) >> 1) * 4 + i * 2 + ((xb_ + 1) & 1)] + bias;
        v.z = Trow[((xb_ + 2) >> 1) * 4 + i * 2 + ((xb_ + 2) & 1)] + bias;
        v.w = Trow[((xb_ + 3) >> 1) * 4 + i * 2 + ((xb_ + 3) & 1)] + bias;
        *(float4*)(row + xb_) = v;
      }
    }
  }
}

extern "C" void kernel_launch(void* const* d_in, const int* in_sizes, int n_in,
                              void* d_out, int out_size, void* d_ws, size_t ws_size,
                              hipStream_t stream) {
  const float* x  = (const float*)d_in[0];   // (4,256,64,64)
  const float* wd = (const float*)d_in[1];   // (64,256,1,1)
  const float* bd = (const float*)d_in[2];   // (64,)
  const float* we = (const float*)d_in[3];   // (100,64,3,3)
  const float* be = (const float*)d_in[4];   // (100,)
  const float* wo = (const float*)d_in[5];   // (256,256,1,1)
  const float* bo = (const float*)d_in[6];   // (256,)
  float* out = (float*)d_out;                // (4,256,128,128)

  // workspace (all 16B-aligned):
  float* enc = (float*)d_ws;                          // 1,638,400 f
  float* zT  = enc + 1638400;                         // 4,734,976 f (padded 68x68)
  __hip_bfloat16* downT = (__hip_bfloat16*)(zT + 4734976);      // 1,115,136 bf16
  unsigned short* Aswz  = (unsigned short*)(downT + (size_t)kN * kTImg); // 64,512
  unsigned short* Awoz  = Aswz + 64512;                          // 81,920

  // 4 dispatches: prep(Awoz only) -> dz GEMM + overlapped extras -> enc GEMM
  //               -> fused out
  k_prep<<<320, 256, 0, stream>>>(wd, wo, Awoz);
  k_dzmfma<<<1024 + kExtraBlocks, 256, 0, stream>>>(x, Awoz, bd, downT, zT, we, Aswz);
  k_encmfma<<<1024, 256, 0, stream>>>(downT, Aswz, be, enc);
  k_fused_out<<<2048, 256, 0, stream>>>(zT, enc, bo, out);
}

// Round 8
// 140.491 us; speedup vs baseline: 1.4176x; 1.0213x over previous
//
#include <hip/hip_runtime.h>
#include <hip/hip_bf16.h>

// CARAFE R14 = R11 (141.6 us anchor; R13 overlap reverted) + bf16 zT:
//  - zT stored as bf16 (was fp32). dz epilogue packs z to bf16 (uint2
//    stores); fused_out loads ushort4 (8B) per tap per og and shifts to
//    f32. Halves the largest remaining stream: zT HBM write 18.9->9.5 MB,
//    fused_out z request bytes 105->52 MB.
//  - Numerics: z passes through one extra bf16 rounding before the
//    softmax-weighted sum -> absmax expected ~0.02-0.03 (was 0.015625).
//    Revert criterion: fail or absmax > ~0.05.
//  - k_prep (737-block R11 form, haloZ shrunk to 8 chunks/px), k_dzmfma v2
//    (LDS x-stage), k_encmfma, k_fused_out v8 (2-og) otherwise unchanged.
// Pipeline: 4 dispatches. N=4, H=W=64, INC=256, CM=64, KUP=5, DELTA=2,
// enc_out=100, OUTC=256.

namespace {
constexpr int kN = 4, kH = 64, kW = 64, kINC = 256, kCM = 64;
constexpr int kENC = 100, kH2 = 128, kW2 = 128, kOUTC = 256;
constexpr int kHW = kH * kW;       // 4096
constexpr int kHW2 = kH2 * kW2;    // 16384
constexpr int kPadW = 66;          // 64 + 1 halo (enc 3x3)
constexpr int kTImg = kPadW * kPadW * kCM;    // 278784 (downT per image)
constexpr int kZPad = 68;          // 64 + 2 halo (reassembly 5x5)
constexpr int kZImg = kZPad * kZPad * kOUTC;  // 1183744 (zT per image, bf16)
constexpr int kXP = 264;           // x-tile LDS pitch in shorts
// k_prep thread-range boundaries:
constexpr int kPrepRepackEnc = 9 * 7 * 2 * 512;          // 64512  (252 blocks)
constexpr int kPrepRepackWoz = 8 * 20 * 512;             // 81920  (320 blocks)
constexpr int kPrepHaloZ = 4 * 528 * 8;                  // 16896 (bf16: 8 f4/px)
constexpr int kPrepHaloD = 4 * 260 * 8;                  // 8320
constexpr int kPrepTotal = kPrepRepackEnc + kPrepRepackWoz + kPrepHaloZ + kPrepHaloD; // 171648
constexpr int kPrepBlocks = (kPrepTotal + 255) / 256;    // 671
}

typedef __attribute__((ext_vector_type(8))) short short8;   // 8 bf16
typedef __attribute__((ext_vector_type(4))) float floatx4;  // MFMA acc

static __device__ __forceinline__ unsigned short bf16bits(float f) {
  __hip_bfloat16 h = __float2bfloat16(f);
  return *(unsigned short*)&h;
}

static __device__ __forceinline__ float bf2f(unsigned short u) {
  union { unsigned int i; float f; } c;
  c.i = ((unsigned int)u) << 16;
  return c.f;
}

// ---------- merged prep: weight repacks + halo clears (one dispatch) ----------
__global__ __launch_bounds__(256) void k_prep(
    const float* __restrict__ we, unsigned short* __restrict__ Aswz,
    const float* __restrict__ wd, const float* __restrict__ wo,
    unsigned short* __restrict__ Awoz,
    __hip_bfloat16* __restrict__ zT, __hip_bfloat16* __restrict__ downT) {
  const int t = blockIdx.x * 256 + threadIdx.x;
  if (t < kPrepRepackEnc) {
    const int e = t;
    const int j = e & 7, lane = (e >> 3) & 63, kh = (e >> 9) & 1, tm = e >> 10;
    const int mt = tm % 7, tap = tm / 7;
    const int o = mt * 16 + (lane & 15);
    const int ci = kh * 32 + ((lane >> 4) & 3) * 8 + j;
    const float v = (o < kENC) ? we[(size_t)o * 576 + ci * 9 + tap] : 0.f;
    Aswz[e] = bf16bits(v);
  } else if (t < kPrepRepackEnc + kPrepRepackWoz) {
    const int e = t - kPrepRepackEnc;
    const int j = e & 7, lane = (e >> 3) & 63;
    const int rest = e >> 9;
    const int mt = rest % 20, ks = rest / 20;
    const int r = mt * 16 + (lane & 15);
    const int k = ks * 32 + (lane >> 4) * 8 + j;
    const float v = (r < kCM) ? wd[(size_t)r * kINC + k]
                              : wo[(size_t)(r - kCM) * kINC + k];
    Awoz[e] = bf16bits(v);
  } else if (t < kPrepTotal) {
    const int u0 = t - (kPrepRepackEnc + kPrepRepackWoz);
    if (u0 < kPrepHaloZ) {
      const int chunk = u0 & 7, rest = u0 >> 3;     // 8 x 16B = 512B/px (bf16)
      const int i = rest % 528, n = rest / 528;
      int r, c;
      if (i < 272) { r = i / 68; if (r >= 2) r += 64; c = i % 68; }
      else { const int j = i - 272; r = 2 + (j >> 2); const int cc = j & 3; c = (cc < 2) ? cc : cc + 64; }
      float4* p = (float4*)((char*)zT
                  + ((size_t)n * kZImg + ((size_t)r * kZPad + c) * kOUTC) * 2) + chunk;
      *p = make_float4(0.f, 0.f, 0.f, 0.f);
    } else {
      const int u = u0 - kPrepHaloZ;
      const int chunk = u & 7, rest = u >> 3;
      const int i = rest % 260, n = rest / 260;
      int r, c;
      if (i < 132) { r = (i / 66) ? 65 : 0; c = i % 66; }
      else { const int j = i - 132; r = 1 + (j >> 1); c = (j & 1) ? 65 : 0; }
      float4* p = (float4*)((char*)downT
                  + ((size_t)n * kTImg + ((size_t)r * kPadW + c) * kCM) * 2) + chunk;
      *p = make_float4(0.f, 0.f, 0.f, 0.f);
    }
  }
}

// ---------- fused down + z GEMM: M=320, K=256, N=16384 (v2 + bf16 z) ----------
__global__ __launch_bounds__(256) void k_dzmfma(
    const float* __restrict__ x, const unsigned short* __restrict__ Awoz,
    const float* __restrict__ bd, __hip_bfloat16* __restrict__ downT,
    __hip_bfloat16* __restrict__ zT) {
  const int b = blockIdx.x;
  const int pt = b & 255, n = b >> 8;
  const int wave = threadIdx.x >> 6, lane = threadIdx.x & 63;
  const int col = lane & 15, quad = lane >> 4;
  const int px = pt * 16 + col;
  const int h = px >> 6, w = px & 63;

  __shared__ unsigned short xlds[16 * kXP];    // [px][ch] bf16, 8448 B

  // --- stage x tile: wave w handles ksteps {2w, 2w+1} ---
  {
    const float* xb = x + (size_t)n * kINC * kHW + px;
#pragma unroll
    for (int ki = 0; ki < 2; ++ki) {
      const int ks = wave * 2 + ki;
      float xv[8];
#pragma unroll
      for (int j = 0; j < 8; ++j)
        xv[j] = xb[(size_t)(ks * 32 + quad * 8 + j) * kHW];
      short8 bf;
#pragma unroll
      for (int j = 0; j < 8; ++j) bf[j] = (short)bf16bits(xv[j]);
      *(short8*)(xlds + col * kXP + ks * 32 + quad * 8) = bf;
    }
  }
  __syncthreads();

  floatx4 acc[5];
#pragma unroll
  for (int m = 0; m < 5; ++m) acc[m] = (floatx4){0.f, 0.f, 0.f, 0.f};

#pragma unroll
  for (int ks = 0; ks < 8; ++ks) {
    const short8 bf = *(const short8*)(xlds + col * kXP + ks * 32 + quad * 8);
#pragma unroll
    for (int m = 0; m < 5; ++m) {
      const int wtile = wave * 5 + m;
      const short8 af = *(const short8*)(
          Awoz + ((size_t)(ks * 20 + wtile) * 64 + lane) * 8);
      acc[m] = __builtin_amdgcn_mfma_f32_16x16x32_bf16(af, bf, acc[m], 0, 0, 0);
    }
  }

#pragma unroll
  for (int m = 0; m < 5; ++m) {
    const int wtile = wave * 5 + m;
    const int r0 = wtile * 16 + quad * 4;
    if (wtile < 4) {
      union { unsigned short u[4]; uint2 v; } pk;
#pragma unroll
      for (int rr = 0; rr < 4; ++rr)
        pk.u[rr] = bf16bits(acc[m][rr] + bd[r0 + rr]);
      __hip_bfloat16* dst = downT + (size_t)n * kTImg
                            + ((h + 1) * kPadW + (w + 1)) * kCM + r0;
      *(uint2*)dst = pk.v;
    } else {
      const int o = r0 - kCM;
      union { unsigned short u[4]; uint2 v; } pk;
#pragma unroll
      for (int rr = 0; rr < 4; ++rr)
        pk.u[rr] = bf16bits(acc[m][rr]);       // z: no bias (bo added in tail)
      __hip_bfloat16* dst = zT + (size_t)n * kZImg
                            + ((h + 2) * kZPad + (w + 2)) * kOUTC + o;
      *(uint2*)dst = pk.v;
    }
  }
}

// ---------- enc conv as MFMA GEMM -> enc fp32 (N,100,64,64) (R4, verified) ----------
// Writes RAW (pre-softmax) enc; softmax happens inside k_fused_out.
__global__ __launch_bounds__(256) void k_encmfma(
    const __hip_bfloat16* __restrict__ downT,
    const unsigned short* __restrict__ Aswz,
    const float* __restrict__ be, float* __restrict__ enc) {
  const int b = blockIdx.x;                 // 1024: h(64) x mtp(4) x n(4)
  const int h = b & 63, mtp = (b >> 6) & 3, n = b >> 8;
  const int wave = threadIdx.x >> 6, lane = threadIdx.x & 63;
  const int w0 = wave << 4;
  const int col = lane & 15, quad = lane >> 4;
  const int mt0 = mtp * 2;
  const bool has2 = (mt0 + 1) < 7;
  const short* dT = (const short*)downT + (size_t)n * kTImg;
  floatx4 acc0 = {0.f, 0.f, 0.f, 0.f}, acc1 = {0.f, 0.f, 0.f, 0.f};
#pragma unroll
  for (int tap = 0; tap < 9; ++tap) {
    const int dh = tap / 3 - 1, dw = tap % 3 - 1;
    const int rowbase = ((h + 1 + dh) * kPadW + (w0 + col + 1 + dw)) * kCM
                        + quad * 8;
#pragma unroll
    for (int kh = 0; kh < 2; ++kh) {
      const short8 bf = *(const short8*)(dT + rowbase + kh * 32);
      const short8 a0 = *(const short8*)(
          Aswz + (((size_t)(tap * 7 + mt0) * 2 + kh) * 64 + lane) * 8);
      acc0 = __builtin_amdgcn_mfma_f32_16x16x32_bf16(a0, bf, acc0, 0, 0, 0);
      if (has2) {
        const short8 a1 = *(const short8*)(
            Aswz + (((size_t)(tap * 7 + mt0 + 1) * 2 + kh) * 64 + lane) * 8);
        acc1 = __builtin_amdgcn_mfma_f32_16x16x32_bf16(a1, bf, acc1, 0, 0, 0);
      }
    }
  }
  const int p = h * kW + w0 + col;
#pragma unroll
  for (int r = 0; r < 4; ++r) {
    const int o = mt0 * 16 + quad * 4 + r;
    if (o < kENC) enc[(size_t)(n * kENC + o) * kHW + p] = acc0[r] + be[o];
  }
  if (has2) {
#pragma unroll
    for (int r = 0; r < 4; ++r) {
      const int o = (mt0 + 1) * 16 + quad * 4 + r;
      if (o < kENC) enc[(size_t)(n * kENC + o) * kHW + p] = acc1[r] + be[o];
    }
  }
}

// ---------- fused softmax + reassembly + pixel shuffle + bias -> out (v8b) ----------
// 2048 blocks: pt(256) x oh(2) x n(4); 256 thr = 4 waves. Each block does
// og = {2*oh, 2*oh+1}: kern tile staged + softmaxed ONCE, reused for both.
// Phase 2 loads z as bf16 ushort4 (8B) and shifts to f32.
__global__ __launch_bounds__(256) void k_fused_out(
    const __hip_bfloat16* __restrict__ zT, const float* __restrict__ enc,
    const float* __restrict__ bo, float* __restrict__ out) {
  const int b = blockIdx.x;
  const int pt = b & 255, oh = (b >> 8) & 1, n = b >> 9;
  const int tid = threadIdx.x;
  const int wave = tid >> 6, lane = tid & 63;
  const int h = pt >> 2, w0 = (pt & 3) << 4;   // 16-px segment [w0, w0+16)
  const int px0 = pt * 16;                     // linear px base

  __shared__ float lds[1664 + 4160];           // 23.3 KB
  float* kernLDS = lds;                        // [16 px][104] (pad 100->104)
  float* scr = lds + 1664;                     // transpose scratch [64][65]

  // --- phase 1a: stage raw kern tile ---
  {
    const int p = tid & 15, chb = tid >> 4;
#pragma unroll
    for (int r = 0; r < 7; ++r) {
      const int ch = r * 16 + chb;
      if (ch < kENC)
        kernLDS[p * 104 + ch] = enc[((size_t)n * kENC + ch) * kHW + px0 + p];
    }
  }
  __syncthreads();

  // --- phase 1b: wave-parallel softmax over 25 taps ---
  {
    const int pair = tid >> 2, q = tid & 3;
    const int p = pair >> 2, d = pair & 3;
    float* kb = kernLDS + p * 104 + d;         // taps at stride 4 floats
    const int start = q ? (1 + 6 * q) : 0;
    const int count = q ? 6 : 7;
    float v[7];
    float m = -1e30f;
#pragma unroll
    for (int k = 0; k < 7; ++k)
      if (k < count) { v[k] = kb[(start + k) * 4]; m = fmaxf(m, v[k]); }
    m = fmaxf(m, __shfl_xor(m, 1));
    m = fmaxf(m, __shfl_xor(m, 2));
    float s = 0.f;
#pragma unroll
    for (int k = 0; k < 7; ++k)
      if (k < count) { v[k] = __expf(v[k] - m); s += v[k]; }
    s += __shfl_xor(s, 1);
    s += __shfl_xor(s, 2);
    const float inv = 1.f / s;
#pragma unroll
    for (int k = 0; k < 7; ++k)
      if (k < count) kb[(start + k) * 4] = v[k] * inv;
  }
  __syncthreads();

  const int oc = lane & 15, pxi = lane >> 4;
  const int px_l = wave * 4 + pxi;             // [0,16)
  const int w = w0 + px_l;
  const int o_l = oc * 4;                      // [0,64) step 4
  const float* kp = kernLDS + px_l * 104;
  const int ol2 = tid >> 2, q2 = tid & 3;      // store-phase mapping

#pragma unroll
  for (int ogi = 0; ogi < 2; ++ogi) {
    const int og = oh * 2 + ogi;

    // --- phase 2: 25 taps, z bf16 ushort4 direct from global ---
    const unsigned short* zb =
        (const unsigned short*)zT + (size_t)n * kZImg + og * 64 + o_l;
    float acc[4][4] = {};                      // [oi][d]
#pragma unroll
    for (int tap = 0; tap < 25; ++tap) {
      const int kh = tap / 5, kw = tap % 5;    // z idx: (h+2 + kh-2) = h+kh
      const ushort4 zu = *(const ushort4*)(
          zb + ((size_t)(h + kh) * kZPad + (w + kw)) * kOUTC);
      const float4 kf = *(const float4*)(kp + tap * 4);
      const float zx = bf2f(zu.x), zy = bf2f(zu.y), zz = bf2f(zu.z), zw = bf2f(zu.w);
      acc[0][0] += zx * kf.x; acc[0][1] += zx * kf.y; acc[0][2] += zx * kf.z; acc[0][3] += zx * kf.w;
      acc[1][0] += zy * kf.x; acc[1][1] += zy * kf.y; acc[1][2] += zy * kf.z; acc[1][3] += zy * kf.w;
      acc[2][0] += zz * kf.x; acc[2][1] += zz * kf.y; acc[2][2] += zz * kf.z; acc[2][3] += zz * kf.w;
      acc[3][0] += zw * kf.x; acc[3][1] += zw * kf.y; acc[3][2] += zw * kf.z; acc[3][3] += zw * kf.w;
    }

    // --- phase 3: transpose via scratch, coalesced stores ---
    __syncthreads();                           // scratch free (prev stores done)
#pragma unroll
    for (int oi = 0; oi < 4; ++oi)
#pragma unroll
      for (int d = 0; d < 4; ++d)
        scr[(o_l + oi) * 65 + px_l * 4 + d] = acc[oi][d];
    __syncthreads();

    const int o = og * 64 + ol2;
    const float bias = bo[o];
    const float* Trow = scr + ol2 * 65;
#pragma unroll
    for (int i = 0; i < 2; ++i) {
      float* row = out + ((size_t)(n * kOUTC + o) * kH2 + (2 * h + i)) * kW2 + 2 * w0;
#pragma unroll
      for (int s = 0; s < 2; ++s) {
        const int xb_ = s * 16 + q2 * 4;       // x offset in [0,32)
        float4 v;
        v.x = Trow[((xb_ + 0) >> 1) * 4 + i * 2 + ((xb_ + 0) & 1)] + bias;
        v.y = Trow[((xb_ + 1) >> 1) * 4 + i * 2 + ((xb_ + 1) & 1)] + bias;
        v.z = Trow[((xb_ + 2) >> 1) * 4 + i * 2 + ((xb_ + 2) & 1)] + bias;
        v.w = Trow[((xb_ + 3) >> 1) * 4 + i * 2 + ((xb_ + 3) & 1)] + bias;
        *(float4*)(row + xb_) = v;
      }
    }
  }
}

extern "C" void kernel_launch(void* const* d_in, const int* in_sizes, int n_in,
                              void* d_out, int out_size, void* d_ws, size_t ws_size,
                              hipStream_t stream) {
  const float* x  = (const float*)d_in[0];   // (4,256,64,64)
  const float* wd = (const float*)d_in[1];   // (64,256,1,1)
  const float* bd = (const float*)d_in[2];   // (64,)
  const float* we = (const float*)d_in[3];   // (100,64,3,3)
  const float* be = (const float*)d_in[4];   // (100,)
  const float* wo = (const float*)d_in[5];   // (256,256,1,1)
  const float* bo = (const float*)d_in[6];   // (256,)
  float* out = (float*)d_out;                // (4,256,128,128)

  // workspace (all 16B-aligned):
  float* enc = (float*)d_ws;                               // 1,638,400 f32
  __hip_bfloat16* zT = (__hip_bfloat16*)(enc + 1638400);   // 4,734,976 bf16
  __hip_bfloat16* downT = zT + (size_t)kN * kZImg;         // 1,115,136 bf16
  unsigned short* Aswz  = (unsigned short*)(downT + (size_t)kN * kTImg); // 64,512
  unsigned short* Awoz  = Aswz + 64512;                    // 81,920

  // 4 dispatches: prep(repacks+halo) -> dz GEMM -> enc GEMM -> fused out
  k_prep<<<kPrepBlocks, 256, 0, stream>>>(we, Aswz, wd, wo, Awoz, zT, downT);
  k_dzmfma<<<1024, 256, 0, stream>>>(x, Awoz, bd, downT, zT);
  k_encmfma<<<1024, 256, 0, stream>>>(downT, Aswz, be, enc);
  k_fused_out<<<2048, 256, 0, stream>>>(zT, enc, bo, out);
}